// Round 1
// baseline (565.311 us; speedup 1.0000x reference)
//
#include <hip/hip_runtime.h>
#include <stdint.h>

#define D 256

__device__ __forceinline__ uint32_t fmono(float f) {
    uint32_t u = __float_as_uint(f);
    return (u & 0x80000000u) ? ~u : (u | 0x80000000u);
}

// ---------------- prep: row norms + init keys/hist ----------------
__global__ void prep_kernel(const float* __restrict__ X, const float* __restrict__ E,
                            float* __restrict__ xn, float* __restrict__ en,
                            unsigned long long* __restrict__ keys,
                            unsigned int* __restrict__ hist, int N, int K)
{
    int gid  = blockIdx.x * blockDim.x + threadIdx.x;
    int wid  = gid >> 6;
    int lane = threadIdx.x & 63;
    int total = N + K;
    if (wid < total) {
        const float* src = (wid < N) ? (X + (size_t)wid * D)
                                     : (E + (size_t)(wid - N) * D);
        float4 v = *(const float4*)(src + lane * 4);
        float s = v.x*v.x + v.y*v.y + v.z*v.z + v.w*v.w;
        #pragma unroll
        for (int o = 32; o >= 1; o >>= 1) s += __shfl_xor(s, o, 64);
        if (lane == 0) { if (wid < N) xn[wid] = s; else en[wid - N] = s; }
    }
    int stride = gridDim.x * blockDim.x;
    for (int i = gid; i < N; i += stride) keys[i] = 0xFFFFFFFFFFFFFFFFull;
    for (int i = gid; i < K; i += stride) hist[i] = 0u;
}

// ---------------- dist GEMM: 128x128 tile, 8x8 microtile ----------------
#define BM 128
#define BN 128
#define BK 8
#define LDP 132

__global__ __launch_bounds__(256, 2) void dist_gemm(
    const float* __restrict__ X, const float* __restrict__ E,
    const float* __restrict__ xn, const float* __restrict__ en,
    float* __restrict__ dist, unsigned long long* __restrict__ keys,
    int N, int K)
{
    __shared__ float As[BK][LDP];
    __shared__ float Bs[BK][LDP];
    const int tid = threadIdx.x;
    const int tx = tid & 15, ty = tid >> 4;
    const int row0 = blockIdx.y * BM, col0 = blockIdx.x * BN;
    const int r  = tid >> 1;          // 0..127
    const int dq = (tid & 1) * 4;     // 0 or 4
    const float* ga = X + (size_t)(row0 + r) * D + dq;
    const float* gb = E + (size_t)(col0 + r) * D + dq;

    float acc[8][8];
    #pragma unroll
    for (int i = 0; i < 8; ++i)
        #pragma unroll
        for (int j = 0; j < 8; ++j) acc[i][j] = 0.0f;

    for (int d0 = 0; d0 < D; d0 += BK) {
        float4 a = *(const float4*)(ga + d0);
        float4 b = *(const float4*)(gb + d0);
        __syncthreads();
        As[dq+0][r] = a.x; As[dq+1][r] = a.y; As[dq+2][r] = a.z; As[dq+3][r] = a.w;
        Bs[dq+0][r] = b.x; Bs[dq+1][r] = b.y; Bs[dq+2][r] = b.z; Bs[dq+3][r] = b.w;
        __syncthreads();
        #pragma unroll
        for (int kk = 0; kk < BK; ++kk) {
            float a0[8], b0[8];
            *(float4*)&a0[0] = *(const float4*)&As[kk][ty*8];
            *(float4*)&a0[4] = *(const float4*)&As[kk][ty*8+4];
            *(float4*)&b0[0] = *(const float4*)&Bs[kk][tx*8];
            *(float4*)&b0[4] = *(const float4*)&Bs[kk][tx*8+4];
            #pragma unroll
            for (int i = 0; i < 8; ++i)
                #pragma unroll
                for (int j = 0; j < 8; ++j) acc[i][j] += a0[i]*b0[j];
        }
    }

    float xr[8], ec[8];
    #pragma unroll
    for (int i = 0; i < 8; ++i) xr[i] = xn[row0 + ty*8 + i];
    #pragma unroll
    for (int j = 0; j < 8; ++j) ec[j] = en[col0 + tx*8 + j];

    unsigned long long best[8];
    #pragma unroll
    for (int i = 0; i < 8; ++i) {
        float dv[8];
        #pragma unroll
        for (int j = 0; j < 8; ++j) dv[j] = xr[i] + ec[j] - 2.0f*acc[i][j];
        size_t base = (size_t)(row0 + ty*8 + i) * K + col0 + tx*8;
        *(float4*)&dist[base]     = make_float4(dv[0], dv[1], dv[2], dv[3]);
        *(float4*)&dist[base + 4] = make_float4(dv[4], dv[5], dv[6], dv[7]);
        unsigned long long bk = 0xFFFFFFFFFFFFFFFFull;
        #pragma unroll
        for (int j = 0; j < 8; ++j) {
            unsigned long long kk2 = ((unsigned long long)fmono(dv[j]) << 32)
                                   | (unsigned)(col0 + tx*8 + j);
            bk = (kk2 < bk) ? kk2 : bk;
        }
        best[i] = bk;
    }
    #pragma unroll
    for (int i = 0; i < 8; ++i) {
        unsigned long long bk = best[i];
        #pragma unroll
        for (int o = 1; o < 16; o <<= 1) {
            unsigned long long other = __shfl_xor(bk, o, 64);
            bk = (other < bk) ? other : bk;
        }
        if (tx == 0) atomicMin(&keys[row0 + ty*8 + i], bk);
    }
}

// ---------------- per-row outputs: quantized, one-hot, idx, hist, loss partial ----------------
__global__ void row_out(const float* __restrict__ X, const float* __restrict__ E,
                        const unsigned long long* __restrict__ keys,
                        float* __restrict__ quant, float* __restrict__ enc,
                        float* __restrict__ idxf, unsigned int* __restrict__ hist,
                        float* __restrict__ partials, int N, int K)
{
    int wid  = (blockIdx.x * blockDim.x + threadIdx.x) >> 6;
    int lane = threadIdx.x & 63;
    if (wid >= N) return;
    int idx = (int)(unsigned)(keys[wid] & 0xFFFFFFFFull);

    float4 x4 = *(const float4*)(X + (size_t)wid * D + lane*4);
    float4 q4 = *(const float4*)(E + (size_t)idx * D + lane*4);
    *(float4*)(quant + (size_t)wid * D + lane*4) = q4;
    float dx = q4.x-x4.x, dy = q4.y-x4.y, dz = q4.z-x4.z, dw = q4.w-x4.w;
    float s = dx*dx + dy*dy + dz*dz + dw*dw;
    #pragma unroll
    for (int o = 32; o >= 1; o >>= 1) s += __shfl_xor(s, o, 64);

    #pragma unroll
    for (int c = 0; c < 4; ++c) {
        int col = c * 256 + lane * 4;
        float4 v;
        v.x = (col + 0 == idx) ? 1.0f : 0.0f;
        v.y = (col + 1 == idx) ? 1.0f : 0.0f;
        v.z = (col + 2 == idx) ? 1.0f : 0.0f;
        v.w = (col + 3 == idx) ? 1.0f : 0.0f;
        *(float4*)(enc + (size_t)wid * K + col) = v;
    }
    if (lane == 0) {
        partials[wid] = s;
        idxf[wid] = (float)idx;
        atomicAdd(&hist[idx], 1u);
    }
}

// ---------------- finalize: vq_loss + perplexity ----------------
__global__ void finalize_kernel(const float* __restrict__ partials,
                                const unsigned int* __restrict__ hist,
                                float* __restrict__ out_loss,
                                float* __restrict__ out_perp,
                                int N, int K)
{
    int tid = threadIdx.x;
    float ls = 0.0f;
    for (int i = tid; i < N; i += 1024) ls += partials[i];
    float ent = 0.0f;
    if (tid < K) {
        float p = (float)hist[tid] / (float)N;
        ent = p * logf(p + 1e-10f);
    }
    #pragma unroll
    for (int o = 32; o >= 1; o >>= 1) {
        ls  += __shfl_xor(ls,  o, 64);
        ent += __shfl_xor(ent, o, 64);
    }
    __shared__ float sl[16], se[16];
    int w = tid >> 6, lane = tid & 63;
    if (lane == 0) { sl[w] = ls; se[w] = ent; }
    __syncthreads();
    if (tid == 0) {
        float L = 0.0f, En = 0.0f;
        for (int i = 0; i < 16; ++i) { L += sl[i]; En += se[i]; }
        *out_loss = 0.25f * L / ((float)N * (float)D);
        *out_perp = expf(-En);
    }
}

extern "C" void kernel_launch(void* const* d_in, const int* in_sizes, int n_in,
                              void* d_out, int out_size, void* d_ws, size_t ws_size,
                              hipStream_t stream)
{
    const float* X = (const float*)d_in[0];
    const float* E = (const float*)d_in[1];
    const int N = in_sizes[0] / D;   // 65536
    const int K = in_sizes[1] / D;   // 1024
    float* out = (float*)d_out;

    const size_t O1 = 1;                          // quantized_st  [N*D]
    const size_t O2 = O1 + (size_t)N * D;         // perplexity    [1]
    const size_t O3 = O2 + 1;                     // encodings     [N*K]
    const size_t O4 = O3 + (size_t)N * K;         // distances     [N*K]
    const size_t O5 = O4 + (size_t)N * K;         // indices       [N]

    char* ws = (char*)d_ws;
    float* xn = (float*)ws;                                        // N floats
    float* en = (float*)(ws + (size_t)N * 4);                      // K floats
    unsigned long long* keys = (unsigned long long*)(ws + (size_t)N*4 + 4096);
    unsigned int* hist = (unsigned int*)(ws + (size_t)N*4 + 4096 + (size_t)N*8);
    float* partials = (float*)(ws + (size_t)N*4 + 4096 + (size_t)N*8 + 4096);

    int prep_blocks = (N + K + 3) / 4;  // 4 waves (rows) per 256-thread block
    prep_kernel<<<prep_blocks, 256, 0, stream>>>(X, E, xn, en, keys, hist, N, K);

    dim3 g(K / BN, N / BM);
    dist_gemm<<<g, 256, 0, stream>>>(X, E, xn, en, out + O4, keys, N, K);

    row_out<<<N / 4, 256, 0, stream>>>(X, E, keys, out + O1, out + O3,
                                       out + O5, hist, partials, N, K);

    finalize_kernel<<<1, 1024, 0, stream>>>(partials, hist, out, out + O2, N, K);
}